// Round 14
// baseline (456.656 us; speedup 1.0000x reference)
//
#include <hip/hip_runtime.h>
#include <hip/hip_bf16.h>

// LinearPreMix: qkv = x @ W_qkv^T, split to q,k,v, reshape [B,S,E]->[B,H,S,DK]
// Pass 1: cast x,W fp32->bf16 into d_ws.
// Pass 2: r14 — r13 persistent 256x256 structure with the MFMA shape switched
//         16x16x32 -> 32x32x16 (shape ceiling 2075 -> ~2450 TF, +20% FLOP per
//         busy cycle at identical LDS traffic). 4 phases per K128 (half the
//         barriers), ring-4 K32 slots, stage p+3 at phase p, W_V8 every phase.

constexpr int Bb = 4, Ss = 4096, Ee = 2048, Hh = 16, Dk = 128;
constexpr int Mm = Bb * Ss;   // 16384
constexpr int Nn = 3 * Ee;    // 6144
constexpr int Kk = Ee;        // 2048

typedef __bf16 bf16_t;
typedef __bf16 bf16x8 __attribute__((ext_vector_type(8)));
typedef float  f32x4  __attribute__((ext_vector_type(4)));
typedef float  f32x16 __attribute__((ext_vector_type(16)));

// ---------------------------------------------------------------- cast pass
__global__ __launch_bounds__(256)
void cast_f32_to_bf16(const float* __restrict__ x, const float* __restrict__ w,
                      bf16_t* __restrict__ xb, bf16_t* __restrict__ wb)
{
    const long XG = (long)Mm * Kk / 8;
    const long TG = XG + (long)Nn * Kk / 8;
    const long stride = (long)gridDim.x * blockDim.x;
    for (long g = (long)blockIdx.x * blockDim.x + threadIdx.x; g < TG; g += stride) {
        const float* s; bf16_t* d;
        if (g < XG) { s = x + g * 8;        d = xb + g * 8; }
        else        { s = w + (g - XG) * 8; d = wb + (g - XG) * 8; }
        f32x4 lo = *(const f32x4*)s;
        f32x4 hi = *(const f32x4*)(s + 4);
        bf16x8 o;
#pragma unroll
        for (int j = 0; j < 4; ++j) { o[j] = (bf16_t)lo[j]; o[j + 4] = (bf16_t)hi[j]; }
        *(bf16x8*)d = o;
    }
}

// ---------------------------------- persistent 256² GEMM, 32x32x16 MFMA
constexpr int BM = 256, BN = 256;
constexpr long BSTEP = (long)1024 * Kk;   // 4 bn-panels of 256 rows

#define GLL16(GSRC, LDST) \
  __builtin_amdgcn_global_load_lds((const __attribute__((address_space(1))) void*)(GSRC), \
                                   (__attribute__((address_space(3))) void*)(LDST), 16, 0, 0)

// stage one K32 slice (A 256x32 + B 256x32) into slot SLOT: 4 GLL16
#define STG32(SLOT, BP0, BP1, KOFS) do { \
    bf16_t* _da = sA + (SLOT) * 8192 + wid * 512; \
    bf16_t* _db = sB + (SLOT) * 8192 + wid * 512; \
    GLL16(srcA0 + (KOFS), _da); \
    GLL16(srcA1 + (KOFS), _da + 4096); \
    GLL16((BP0) + (KOFS), _db); \
    GLL16((BP1) + (KOFS), _db + 4096); \
} while (0)

// phase (slot J): 12 ds_read | stage slice +3 -> slot (J+3)&3 | barrier |
// 16 x mfma_32x32x16 | W_V8 | barrier
#define PH32(J, BP0, BP1, KOFS) do { \
    bf16x8 a0[4], a1[4], b0[2], b1[2]; \
    _Pragma("unroll") \
    for (int mb = 0; mb < 4; ++mb) { \
        int r = wm * 128 + mb * 32 + (lane & 31); \
        int c0 = (lane >> 5); \
        int c1 = 2 + (lane >> 5); \
        a0[mb] = *(const bf16x8*)(sA + (J) * 8192 + (r * 4 + (c0 ^ ((r >> 1) & 3))) * 8); \
        a1[mb] = *(const bf16x8*)(sA + (J) * 8192 + (r * 4 + (c1 ^ ((r >> 1) & 3))) * 8); \
    } \
    _Pragma("unroll") \
    for (int nb = 0; nb < 2; ++nb) { \
        int cr = wn * 64 + nb * 32 + (lane & 31); \
        int c0 = (lane >> 5); \
        int c1 = 2 + (lane >> 5); \
        b0[nb] = *(const bf16x8*)(sB + (J) * 8192 + (cr * 4 + (c0 ^ ((cr >> 1) & 3))) * 8); \
        b1[nb] = *(const bf16x8*)(sB + (J) * 8192 + (cr * 4 + (c1 ^ ((cr >> 1) & 3))) * 8); \
    } \
    STG32((((J) + 3) & 3), BP0, BP1, KOFS); \
    __builtin_amdgcn_s_barrier(); \
    __builtin_amdgcn_s_setprio(1); \
    _Pragma("unroll") \
    for (int mb = 0; mb < 4; ++mb) { \
        _Pragma("unroll") \
        for (int nb = 0; nb < 2; ++nb) { \
            acc[mb][nb] = __builtin_amdgcn_mfma_f32_32x32x16_bf16( \
                a0[mb], b0[nb], acc[mb][nb], 0, 0, 0); \
            acc[mb][nb] = __builtin_amdgcn_mfma_f32_32x32x16_bf16( \
                a1[mb], b1[nb], acc[mb][nb], 0, 0, 0); \
        } \
    } \
    __builtin_amdgcn_s_setprio(0); \
    asm volatile("s_waitcnt vmcnt(8)" ::: "memory"); \
    __builtin_amdgcn_s_barrier(); \
} while (0)

__global__ __launch_bounds__(512, 2)
void qkv_p32(const bf16_t* __restrict__ xb, const bf16_t* __restrict__ wb,
             float* __restrict__ out)
{
    extern __shared__ __attribute__((aligned(16))) char smem_raw[];
    bf16_t* sA = (bf16_t*)smem_raw;                 // 4 slots x 8192 bf16 (64 KiB)
    bf16_t* sB = (bf16_t*)(smem_raw + 65536);       // 4 slots x 8192 bf16 (64 KiB)

    const int tid  = threadIdx.x;
    const int lane = tid & 63;
    const int wid  = tid >> 6;     // 0..7
    const int wm   = wid >> 2;     // 0..1 (128-row half)
    const int wn   = wid & 3;      // 0..3 (64-col quarter)

    // persistent mapping: 256 blocks = 8 XCD x 32 CU; fixed bm stripe per XCD;
    // bn walks bn0 + 4t over 6 tiles.
    const int xcd = blockIdx.x & 7;
    const int cu  = blockIdx.x >> 3;       // 0..31
    const int bm  = xcd * 8 + (cu >> 2);   // 0..63
    const int bn0 = cu & 3;                // 0..3
    const int m0  = bm * BM;

    // pre-swizzled staging sources (linear LDS dest + swizzled global source)
    const int r0  = tid >> 2;
    const int cl0 = (tid & 3) ^ ((r0 >> 1) & 3);
    const bf16_t* srcA0 = xb + (size_t)(m0 + r0) * Kk + cl0 * 8;
    const bf16_t* srcA1 = srcA0 + (size_t)128 * Kk;
    const bf16_t* cB0 = wb + (size_t)(bn0 * 256 + r0) * Kk + cl0 * 8;
    const bf16_t* cB1 = cB0 + (size_t)128 * Kk;
    const bf16_t* nB0 = cB0 + BSTEP;
    const bf16_t* nB1 = cB1 + BSTEP;

    const int bbx = m0 >> 12;
    const int s0w = (m0 & (Ss - 1)) + wm * 128;

    f32x16 acc[4][2] = {};
    const f32x16 zero16 = {};

    // prologue: stage slices 0,1,2 into slots 0,1,2; confirm slice 0
    STG32(0, cB0, cB1, 0);
    STG32(1, cB0, cB1, 32);
    STG32(2, cB0, cB1, 64);
    asm volatile("s_waitcnt vmcnt(8)" ::: "memory");
    __builtin_amdgcn_s_barrier();

#pragma unroll 1
    for (int t = 0; t < 6; ++t) {
#pragma unroll 1
        for (int sq = 0; sq < 16; ++sq) {
            const int kb = sq * 128;
            // phase j consumes slice sq*4+j, stages slice +3 (k wraps &2047;
            // at sq==15, j>=1 the staged slice belongs to the NEXT tile:
            // A wraps to k=0/32/64 of the SAME panel (real data), B switches.
            const bf16_t* tb0 = (sq == 15) ? nB0 : cB0;
            const bf16_t* tb1 = (sq == 15) ? nB1 : cB1;
            PH32(0, cB0, cB1, (kb +  96) & 2047);
            PH32(1, tb0, tb1, (kb + 128) & 2047);
            PH32(2, tb0, tb1, (kb + 160) & 2047);
            PH32(3, tb0, tb1, (kb + 192) & 2047);
        }

        // ---- tile boundary: nt store burst (32-lane 128B lines), zero, advance
        {
            const int n0    = (bn0 + 4 * t) * BN;
            const int which = n0 >> 11;
            const int hh    = ((n0 & (Ee - 1)) >> 7) + (wn >> 1);
            float* obase = out + (((size_t)(which * Bb + bbx) * Hh + hh) * Ss + s0w) * Dk
                         + (wn & 1) * 64;
#pragma unroll
            for (int mb = 0; mb < 4; ++mb)
#pragma unroll
                for (int rg = 0; rg < 16; ++rg) {
                    const int row = mb * 32 + (rg & 3) + 8 * (rg >> 2) + 4 * (lane >> 5);
#pragma unroll
                    for (int nb = 0; nb < 2; ++nb)
                        __builtin_nontemporal_store(
                            acc[mb][nb][rg],
                            &obase[(size_t)row * Dk + nb * 32 + (lane & 31)]);
                }
#pragma unroll
            for (int mb = 0; mb < 4; ++mb)
#pragma unroll
                for (int nb = 0; nb < 2; ++nb)
                    acc[mb][nb] = zero16;

            cB0 = nB0; cB1 = nB1;
            if (t == 4) { nB0 -= 5 * BSTEP; nB1 -= 5 * BSTEP; }  // wrap: junk tail of t=5
            else        { nB0 += BSTEP;     nB1 += BSTEP;     }
        }
    }

    // drain remaining (junk) GLLs and stores before exit
    asm volatile("s_waitcnt vmcnt(0)" ::: "memory");
}

// ------------------------------------------- fallback (fp32 reg staging)
constexpr int FTM = 128, FTN = 128, FTK = 64;
constexpr int FNKT = Kk / FTK;

__global__ __launch_bounds__(256, 2)
void qkv_gemm_fb(const float* __restrict__ x, const float* __restrict__ w,
                 float* __restrict__ out)
{
    __shared__ __attribute__((aligned(16))) bf16_t lA[2][FTM * FTK];
    __shared__ __attribute__((aligned(16))) bf16_t lB[2][FTN * FTK];

    const int tid = threadIdx.x, lane = tid & 63, wid = tid >> 6;
    const int wm = wid >> 1, wn = wid & 1;
    const int n0 = blockIdx.x * FTN, m0 = blockIdx.y * FTM;
    f32x4 ra[8], rb[8];

    auto load_regs = [&](int kt) {
        const int k0 = kt * FTK;
#pragma unroll
        for (int i = 0; i < 4; ++i) {
            const int c = tid + i * 256, row = c >> 3, cir = c & 7;
            const float* pa = x + (size_t)(m0 + row) * Kk + k0 + cir * 8;
            const float* pb = w + (size_t)(n0 + row) * Kk + k0 + cir * 8;
            ra[i*2+0] = *(const f32x4*)(pa); ra[i*2+1] = *(const f32x4*)(pa+4);
            rb[i*2+0] = *(const f32x4*)(pb); rb[i*2+1] = *(const f32x4*)(pb+4);
        }
    };
    auto store_lds = [&](int buf) {
#pragma unroll
        for (int i = 0; i < 4; ++i) {
            const int c = tid + i * 256, row = c >> 3, cir = c & 7;
            const int chunk = row * 8 + (cir ^ (row & 7));
            bf16x8 va, vb;
#pragma unroll
            for (int j = 0; j < 4; ++j) {
                va[j] = (bf16_t)ra[i*2+0][j]; va[j+4] = (bf16_t)ra[i*2+1][j];
                vb[j] = (bf16_t)rb[i*2+0][j]; vb[j+4] = (bf16_t)rb[i*2+1][j];
            }
            *(bf16x8*)(&lA[buf][chunk*8]) = va;
            *(bf16x8*)(&lB[buf][chunk*8]) = vb;
        }
    };
    f32x4 acc[4][4] = {};
    auto compute = [&](int buf) {
#pragma unroll
        for (int ks = 0; ks < 2; ++ks) {
            bf16x8 af[4], bfr[4];
#pragma unroll
            for (int mi = 0; mi < 4; ++mi) {
                const int row = wm*64 + mi*16 + (lane & 15);
                const int cir = ks*4 + (lane >> 4);
                af[mi] = *(const bf16x8*)(&lA[buf][(row*8 + (cir ^ (row & 7)))*8]);
            }
#pragma unroll
            for (int ni = 0; ni < 4; ++ni) {
                const int row = wn*64 + ni*16 + (lane & 15);
                const int cir = ks*4 + (lane >> 4);
                bfr[ni] = *(const bf16x8*)(&lB[buf][(row*8 + (cir ^ (row & 7)))*8]);
            }
#pragma unroll
            for (int mi = 0; mi < 4; ++mi)
#pragma unroll
                for (int ni = 0; ni < 4; ++ni)
                    acc[mi][ni] = __builtin_amdgcn_mfma_f32_16x16x32_bf16(af[mi], bfr[ni], acc[mi][ni], 0, 0, 0);
        }
    };

    load_regs(0); store_lds(0);
    int cur = 0;
#pragma unroll 1
    for (int kt = 0; kt < FNKT; ++kt) {
        __syncthreads();
        if (kt + 1 < FNKT) load_regs(kt + 1);
        compute(cur);
        if (kt + 1 < FNKT) store_lds(cur ^ 1);
        cur ^= 1;
    }
    const int b = m0 / Ss, s0g = m0 % Ss;
    const int which = n0 >> 11, h = (n0 & (Ee - 1)) >> 7;
    float* obase = out + ((size_t)((which * Bb + b) * Hh + h) * Ss + s0g) * Dk;
#pragma unroll
    for (int mi = 0; mi < 4; ++mi)
#pragma unroll
        for (int ni = 0; ni < 4; ++ni)
#pragma unroll
            for (int r = 0; r < 4; ++r) {
                const int rowL = wm*64 + mi*16 + (lane >> 4)*4 + r;
                const int colL = wn*64 + ni*16 + (lane & 15);
                obase[(size_t)rowL * Dk + colL] = acc[mi][ni][r];
            }
}

// ---------------------------------------------------------------- launcher
extern "C" void kernel_launch(void* const* d_in, const int* in_sizes, int n_in,
                              void* d_out, int out_size, void* d_ws, size_t ws_size,
                              hipStream_t stream) {
    const float* x = (const float*)d_in[0];
    const float* w = (const float*)d_in[1];
    float* out = (float*)d_out;

    const size_t xb_bytes = (size_t)Mm * Kk * 2;
    const size_t wb_bytes = (size_t)Nn * Kk * 2;

    if (ws_size >= xb_bytes + wb_bytes) {
        bf16_t* xb = (bf16_t*)d_ws;
        bf16_t* wb = (bf16_t*)((char*)d_ws + xb_bytes);
        cast_f32_to_bf16<<<2048, 256, 0, stream>>>(x, w, xb, wb);
        hipFuncSetAttribute((const void*)qkv_p32,
                            hipFuncAttributeMaxDynamicSharedMemorySize, 131072);
        qkv_p32<<<256, 512, 131072, stream>>>(xb, wb, out);
    } else {
        dim3 grid(Nn / FTN, Mm / FTM);
        qkv_gemm_fb<<<grid, dim3(256), 0, stream>>>(x, w, out);
    }
}

// Round 16
// 275.001 us; speedup vs baseline: 1.6606x; 1.6606x over previous
//
#include <hip/hip_runtime.h>
#include <hip/hip_bf16.h>

// LinearPreMix: qkv = x @ W_qkv^T, split to q,k,v, reshape [B,S,E]->[B,H,S,DK]
// r16: INT8 path, r15 with the quant-store addressing bug fixed (was writing
//      float-stride offsets into a char* buffer -> OOB over rows and into the
//      scale arrays -> NaN scales). Pass 1: per-row symmetric i8 quant.
//      Pass 2: r13's persistent 256x256 8-phase structure, slice=K64 i8,
//      mfma_i32_16x16x64_i8 (2x K per instr -> half the phases), epilogue
//      dequant out = acc * sa[row] * sb[col], nt stores.

constexpr int Bb = 4, Ss = 4096, Ee = 2048, Hh = 16, Dk = 128;
constexpr int Mm = Bb * Ss;   // 16384
constexpr int Nn = 3 * Ee;    // 6144
constexpr int Kk = Ee;        // 2048

typedef int   v4i   __attribute__((ext_vector_type(4)));
typedef float f32x4 __attribute__((ext_vector_type(4)));
typedef __bf16 bf16_t;
typedef __bf16 bf16x8 __attribute__((ext_vector_type(8)));

// ------------------------------------------------------- per-row i8 quant
__global__ __launch_bounds__(256)
void quant_rows(const float* __restrict__ x, const float* __restrict__ w,
                char* __restrict__ xq, char* __restrict__ wq,
                float* __restrict__ sa, float* __restrict__ sb)
{
    const int wid  = threadIdx.x >> 6;
    const int lane = threadIdx.x & 63;
    const int row  = blockIdx.x * 4 + wid;          // 0..22527
    const float* src; char* dst; float* sc; int srow;
    if (row < Mm) { src = x + (size_t)row * Kk;        dst = xq + (size_t)row * Kk;        sc = sa; srow = row; }
    else          { src = w + (size_t)(row - Mm) * Kk; dst = wq + (size_t)(row - Mm) * Kk; sc = sb; srow = row - Mm; }

    f32x4 v[8];
    float m = 0.f;
#pragma unroll
    for (int j = 0; j < 8; ++j) {
        v[j] = *(const f32x4*)(src + j * 256 + lane * 4);
#pragma unroll
        for (int e = 0; e < 4; ++e) m = fmaxf(m, fabsf(v[j][e]));
    }
#pragma unroll
    for (int off = 32; off; off >>= 1) m = fmaxf(m, __shfl_xor(m, off));
    m = fmaxf(m, 1e-20f);
    const float inv = 127.f / m;

#pragma unroll
    for (int j = 0; j < 8; ++j) {
        int pk = 0;
#pragma unroll
        for (int e = 0; e < 4; ++e) {
            int q = __float2int_rn(v[j][e] * inv);
            pk |= (q & 0xff) << (e * 8);
        }
        // i8 buffer: element index == byte offset (r15 bug: used float stride)
        *(int*)(dst + j * 256 + lane * 4) = pk;
    }
    if (lane == 0) sc[srow] = m / 127.f;
}

// ---------------------------------- persistent 256² GEMM, i8 K64 slices
constexpr int BM = 256, BN = 256;
constexpr long BSTEP = (long)1024 * Kk;   // 4 bn-panels of 256 rows (chars)

#define GLL16(GSRC, LDST) \
  __builtin_amdgcn_global_load_lds((const __attribute__((address_space(1))) void*)(GSRC), \
                                   (__attribute__((address_space(3))) void*)(LDST), 16, 0, 0)

// slot = 16 KB (256 rows x 64 i8); wave writes 1 KB per GLL
#define STAGE_A(BUF, KH, KOFS) do { \
    char* _d = sA + ((BUF) * 2 + (KH)) * 16384 + wid * 1024; \
    GLL16(srcA0 + (KOFS), _d); \
    GLL16(srcA1 + (KOFS), _d + 8192); \
} while (0)

#define STAGE_B(BUF, KH, P0, P1, KOFS) do { \
    char* _d = sB + ((BUF) * 2 + (KH)) * 16384 + wid * 1024; \
    GLL16((P0) + (KOFS), _d); \
    GLL16((P1) + (KOFS), _d + 8192); \
} while (0)

#define W_NOW ((void)0)
#define W_V4  asm volatile("s_waitcnt vmcnt(4)" ::: "memory")

// phase: ds-reads | stage | barrier | setprio + 16 x mfma_i32_16x16x64_i8 |
// counted vmcnt | barrier.  (r12/r13 discipline: no sched_barrier pins.)
#define PHASE(BUF, KS, MH, LOADB, STAGE, WAIT) do { \
    v4i a[4]; \
    _Pragma("unroll") \
    for (int mf = 0; mf < 4; ++mf) { \
        int r = wm * 128 + (MH) * 64 + mf * 16 + (lane & 15); \
        int q = r * 4 + (kc ^ ((r >> 1) & 3)); \
        a[mf] = *(const v4i*)(sA + ((BUF) * 2 + (KS)) * 16384 + q * 16); \
    } \
    if (LOADB) { \
        _Pragma("unroll") \
        for (int nf = 0; nf < 4; ++nf) { \
            int cr = wn * 64 + nf * 16 + (lane & 15); \
            int q = cr * 4 + (kc ^ ((cr >> 1) & 3)); \
            b[nf] = *(const v4i*)(sB + ((BUF) * 2 + (KS)) * 16384 + q * 16); \
        } \
    } \
    STAGE; \
    __builtin_amdgcn_s_barrier(); \
    __builtin_amdgcn_s_setprio(1); \
    _Pragma("unroll") \
    for (int mf = 0; mf < 4; ++mf) { \
        _Pragma("unroll") \
        for (int nf = 0; nf < 4; ++nf) \
            acc[(MH) * 4 + mf][nf] = __builtin_amdgcn_mfma_i32_16x16x64_i8( \
                a[mf], b[nf], acc[(MH) * 4 + mf][nf], 0, 0, 0); \
    } \
    __builtin_amdgcn_s_setprio(0); \
    WAIT; \
    __builtin_amdgcn_s_barrier(); \
} while (0)

__global__ __launch_bounds__(512, 2)
void qkv_i8(const char* __restrict__ xq, const char* __restrict__ wq,
            const float* __restrict__ sa, const float* __restrict__ sb,
            float* __restrict__ out)
{
    extern __shared__ __attribute__((aligned(16))) char smem_raw[];
    char* sA = smem_raw;                 // [2 buf][2 kh][16384]  64 KiB
    char* sB = smem_raw + 65536;         // [2 buf][2 kh][16384]  64 KiB

    const int tid  = threadIdx.x;
    const int lane = tid & 63;
    const int wid  = tid >> 6;     // 0..7
    const int wm   = wid >> 2;     // 0..1 (128-row half)
    const int wn   = wid & 3;      // 0..3 (64-col quarter)
    const int kc   = lane >> 4;    // frag k-chunk 0..3 (16B = 16 i8 = K16)

    // persistent mapping (r13): 256 blocks, fixed bm stripe/XCD, bn walks +4.
    const int xcd = blockIdx.x & 7;
    const int cu  = blockIdx.x >> 3;       // 0..31
    const int bm  = xcd * 8 + (cu >> 2);   // 0..63
    const int bn0 = cu & 3;                // 0..3
    const int m0  = bm * BM;

    // pre-swizzled staging sources (linear LDS dest + swizzled global source)
    const int r0  = tid >> 2;
    const int cl0 = (tid & 3) ^ ((r0 >> 1) & 3);
    const char* srcA0 = xq + (size_t)(m0 + r0) * Kk + cl0 * 16;
    const char* srcA1 = srcA0 + (size_t)128 * Kk;
    const char* cB0 = wq + (size_t)(bn0 * 256 + r0) * Kk + cl0 * 16;
    const char* cB1 = cB0 + (size_t)128 * Kk;
    const char* nB0 = cB0 + BSTEP;
    const char* nB1 = cB1 + BSTEP;

    const int bbx = m0 >> 12;
    const int s0w = (m0 & (Ss - 1)) + wm * 128;

    v4i b[4];
    v4i acc[8][4] = {};
    const v4i zero4 = {0, 0, 0, 0};

    // prologue: stage buf0 (kh0,kh1 = slices 0,1) + buf1 kh0 (slice 2)
    STAGE_A(0, 0, 0);   STAGE_B(0, 0, cB0, cB1, 0);
    STAGE_A(0, 1, 64);  STAGE_B(0, 1, cB0, cB1, 64);
    STAGE_A(1, 0, 128); STAGE_B(1, 0, cB0, cB1, 128);
    W_V4;
    __builtin_amdgcn_s_barrier();

#pragma unroll 1
    for (int t = 0; t < 6; ++t) {
#pragma unroll 1
        for (int it = 0; it < 8; ++it) {          // octet = K256 = 4 K64-slices
            const int kb = it * 256;
            // stages at +256/+320/+384 wrap to next tile at it==7 (B switches)
            const char* tb0 = (it == 7) ? nB0 : cB0;
            const char* tb1 = (it == 7) ? nB1 : cB1;
            PHASE(0, 0, 0, 1, STAGE_A(1, 1, (kb + 192) & 2047),           W_NOW);
            PHASE(0, 0, 1, 0, STAGE_B(1, 1, cB0, cB1, (kb + 192) & 2047), W_NOW);
            PHASE(0, 1, 0, 1, STAGE_A(0, 0, (kb + 256) & 2047),           W_NOW);
            PHASE(0, 1, 1, 0, STAGE_B(0, 0, tb0, tb1, (kb + 256) & 2047), W_V4);
            PHASE(1, 0, 0, 1, STAGE_A(0, 1, (kb + 320) & 2047),           W_NOW);
            PHASE(1, 0, 1, 0, STAGE_B(0, 1, tb0, tb1, (kb + 320) & 2047), W_NOW);
            PHASE(1, 1, 0, 1, STAGE_A(1, 0, (kb + 384) & 2047),           W_NOW);
            PHASE(1, 1, 1, 0, STAGE_B(1, 0, tb0, tb1, (kb + 384) & 2047), W_V4);
        }

        // ---- tile boundary: dequant + full-line nt store burst, zero, advance
        {
            const int n0    = (bn0 + 4 * t) * BN;
            const int which = n0 >> 11;
            const int hh    = ((n0 & (Ee - 1)) >> 7) + (wn >> 1);
            float* obase = out + (((size_t)(which * Bb + bbx) * Hh + hh) * Ss + s0w) * Dk
                         + (wn & 1) * 64;
            float sbv[4];
#pragma unroll
            for (int nf = 0; nf < 4; ++nf)
                sbv[nf] = sb[n0 + wn * 64 + nf * 16 + (lane & 15)];

#pragma unroll
            for (int mh = 0; mh < 2; ++mh)
#pragma unroll
                for (int mf = 0; mf < 4; ++mf)
#pragma unroll
                    for (int r = 0; r < 4; ++r) {
                        const int row  = mh * 64 + mf * 16 + (lane >> 4) * 4 + r;
                        const float sav = sa[m0 + wm * 128 + row];
#pragma unroll
                        for (int nf = 0; nf < 4; ++nf) {
                            const int col = nf * 16 + (lane & 15);
                            __builtin_nontemporal_store(
                                (float)acc[mh * 4 + mf][nf][r] * sav * sbv[nf],
                                &obase[(size_t)row * Dk + col]);
                        }
                    }
#pragma unroll
            for (int i = 0; i < 8; ++i)
#pragma unroll
                for (int nf = 0; nf < 4; ++nf)
                    acc[i][nf] = zero4;

            cB0 = nB0; cB1 = nB1;
            if (t == 4) { nB0 -= 5 * BSTEP; nB1 -= 5 * BSTEP; }
            else        { nB0 += BSTEP;     nB1 += BSTEP;     }
        }
    }

    asm volatile("s_waitcnt vmcnt(0)" ::: "memory");
}

// ------------------------------------------- fallback (fp32 reg staging)
constexpr int FTM = 128, FTN = 128, FTK = 64;
constexpr int FNKT = Kk / FTK;

__global__ __launch_bounds__(256, 2)
void qkv_gemm_fb(const float* __restrict__ x, const float* __restrict__ w,
                 float* __restrict__ out)
{
    __shared__ __attribute__((aligned(16))) bf16_t lA[2][FTM * FTK];
    __shared__ __attribute__((aligned(16))) bf16_t lB[2][FTN * FTK];

    const int tid = threadIdx.x, lane = tid & 63, wid = tid >> 6;
    const int wm = wid >> 1, wn = wid & 1;
    const int n0 = blockIdx.x * FTN, m0 = blockIdx.y * FTM;
    f32x4 ra[8], rb[8];

    auto load_regs = [&](int kt) {
        const int k0 = kt * FTK;
#pragma unroll
        for (int i = 0; i < 4; ++i) {
            const int c = tid + i * 256, row = c >> 3, cir = c & 7;
            const float* pa = x + (size_t)(m0 + row) * Kk + k0 + cir * 8;
            const float* pb = w + (size_t)(n0 + row) * Kk + k0 + cir * 8;
            ra[i*2+0] = *(const f32x4*)(pa); ra[i*2+1] = *(const f32x4*)(pa+4);
            rb[i*2+0] = *(const f32x4*)(pb); rb[i*2+1] = *(const f32x4*)(pb+4);
        }
    };
    auto store_lds = [&](int buf) {
#pragma unroll
        for (int i = 0; i < 4; ++i) {
            const int c = tid + i * 256, row = c >> 3, cir = c & 7;
            const int chunk = row * 8 + (cir ^ (row & 7));
            bf16x8 va, vb;
#pragma unroll
            for (int j = 0; j < 4; ++j) {
                va[j] = (bf16_t)ra[i*2+0][j]; va[j+4] = (bf16_t)ra[i*2+1][j];
                vb[j] = (bf16_t)rb[i*2+0][j]; vb[j+4] = (bf16_t)rb[i*2+1][j];
            }
            *(bf16x8*)(&lA[buf][chunk*8]) = va;
            *(bf16x8*)(&lB[buf][chunk*8]) = vb;
        }
    };
    f32x4 acc[4][4] = {};
    auto compute = [&](int buf) {
#pragma unroll
        for (int ks = 0; ks < 2; ++ks) {
            bf16x8 af[4], bfr[4];
#pragma unroll
            for (int mi = 0; mi < 4; ++mi) {
                const int row = wm*64 + mi*16 + (lane & 15);
                const int cir = ks*4 + (lane >> 4);
                af[mi] = *(const bf16x8*)(&lA[buf][(row*8 + (cir ^ (row & 7)))*8]);
            }
#pragma unroll
            for (int ni = 0; ni < 4; ++ni) {
                const int row = wn*64 + ni*16 + (lane & 15);
                const int cir = ks*4 + (lane >> 4);
                bfr[ni] = *(const bf16x8*)(&lB[buf][(row*8 + (cir ^ (row & 7)))*8]);
            }
#pragma unroll
            for (int mi = 0; mi < 4; ++mi)
#pragma unroll
                for (int ni = 0; ni < 4; ++ni)
                    acc[mi][ni] = __builtin_amdgcn_mfma_f32_16x16x32_bf16(af[mi], bfr[ni], acc[mi][ni], 0, 0, 0);
        }
    };

    load_regs(0); store_lds(0);
    int cur = 0;
#pragma unroll 1
    for (int kt = 0; kt < FNKT; ++kt) {
        __syncthreads();
        if (kt + 1 < FNKT) load_regs(kt + 1);
        compute(cur);
        if (kt + 1 < FNKT) store_lds(cur ^ 1);
        cur ^= 1;
    }
    const int b = m0 / Ss, s0g = m0 % Ss;
    const int which = n0 >> 11, h = (n0 & (Ee - 1)) >> 7;
    float* obase = out + ((size_t)((which * Bb + b) * Hh + h) * Ss + s0g) * Dk;
#pragma unroll
    for (int mi = 0; mi < 4; ++mi)
#pragma unroll
        for (int ni = 0; ni < 4; ++ni)
#pragma unroll
            for (int r = 0; r < 4; ++r) {
                const int rowL = wm*64 + mi*16 + (lane >> 4)*4 + r;
                const int colL = wn*64 + ni*16 + (lane & 15);
                obase[(size_t)rowL * Dk + colL] = acc[mi][ni][r];
            }
}

// ---------------------------------------------------------------- launcher
extern "C" void kernel_launch(void* const* d_in, const int* in_sizes, int n_in,
                              void* d_out, int out_size, void* d_ws, size_t ws_size,
                              hipStream_t stream) {
    const float* x = (const float*)d_in[0];
    const float* w = (const float*)d_in[1];
    float* out = (float*)d_out;

    const size_t xq_bytes = (size_t)Mm * Kk;            // 33.5 MB
    const size_t wq_bytes = (size_t)Nn * Kk;            // 12.6 MB
    const size_t sa_bytes = (size_t)Mm * 4;
    const size_t sb_bytes = (size_t)Nn * 4;

    if (ws_size >= xq_bytes + wq_bytes + sa_bytes + sb_bytes) {
        char*  xq = (char*)d_ws;
        char*  wq = xq + xq_bytes;
        float* sa = (float*)(wq + wq_bytes);
        float* sb = sa + Mm;

        quant_rows<<<(Mm + Nn) / 4, 256, 0, stream>>>(x, w, xq, wq, sa, sb);
        hipFuncSetAttribute((const void*)qkv_i8,
                            hipFuncAttributeMaxDynamicSharedMemorySize, 131072);
        qkv_i8<<<256, 512, 131072, stream>>>(xq, wq, sa, sb, out);
    } else {
        dim3 grid(Nn / FTN, Mm / FTM);
        qkv_gemm_fb<<<grid, dim3(256), 0, stream>>>(x, w, out);
    }
}